// Round 7
// baseline (449.448 us; speedup 1.0000x reference)
//
#include <hip/hip_runtime.h>
#include <stdint.h>

#define TT 50
#define NSTEP 49
#define NBATCH 4096
#define SS 100
#define HH 256
#define K1 128      // padded K for GEMM1 (S=100 -> 128)
#define NO 128      // padded N for GEMM3 (C=100 -> 128)
#define MROWS 16
#define NBLK 256
#define NTHR 512    // 8 waves

typedef short bf16x8 __attribute__((ext_vector_type(8)));
typedef float f32x4 __attribute__((ext_vector_type(4)));

#define MFMA(a, b, c) __builtin_amdgcn_mfma_f32_16x16x32_bf16((a), (b), (c), 0, 0, 0)

// Fragment-linear weight layouts: [t][nt][ks][lane][8 bf16], 16B per lane.
#define W1G_OFF(t, nt, ks) ((((size_t)(t) * 16 + (nt)) * 4 + (ks)) * 512)
#define W2G_OFF(t, nt, ks) ((((size_t)(t) * 16 + (nt)) * 8 + (ks)) * 512)
#define WOG_OFF(t, nt, ks) ((((size_t)(t) * 8 + (nt)) * 8 + (ks)) * 512)
#define N_W1G W1G_OFF(TT, 0, 0)
#define N_W2G W2G_OFF(TT, 0, 0)
#define N_WOG WOG_OFF(TT, 0, 0)

// LDS-only barrier: waits ds ops but does NOT drain vmcnt, so in-flight
// global_load_lds DMAs keep flying across the sync.
__device__ __forceinline__ void bar_lds() {
  __asm__ volatile("s_waitcnt lgkmcnt(0)\n\ts_barrier" ::: "memory");
}
// Drain the async global->LDS queue (and any other vm ops).
__device__ __forceinline__ void wait_vm0() {
  __asm__ volatile("s_waitcnt vmcnt(0)" ::: "memory");
}

__device__ __forceinline__ short f2b(float f) {
  union { float f; uint32_t u; } v;
  v.f = f;
  return (short)((v.u + 0x7FFFu + ((v.u >> 16) & 1u)) >> 16);
}

__device__ __forceinline__ bf16x8 cvt8(const float* __restrict__ p) {
  bf16x8 r;
#pragma unroll
  for (int j = 0; j < 8; ++j) r[j] = f2b(p[j]);
  return r;
}

__device__ __forceinline__ bf16x8 ldpad(const float* __restrict__ rowp, int k, int kmax) {
  bf16x8 r;
#pragma unroll
  for (int j = 0; j < 8; ++j) {
    int kk = k + j;
    r[j] = (kk < kmax) ? f2b(rowp[kk]) : (short)0;
  }
  return r;
}

__global__ void zero_out(float* out) {
  if (threadIdx.x == 0 && blockIdx.x == 0) out[0] = 0.f;
}

// Coalesced prep: stage a 16-row chunk in LDS (contiguous global reads),
// emit fragment-linear bf16 (contiguous global writes).
__global__ __launch_bounds__(256) void prep(
    const float* __restrict__ W1, const float* __restrict__ b1,
    const float* __restrict__ W2, const float* __restrict__ Wo,
    short* __restrict__ W1g, short* __restrict__ W2g, short* __restrict__ Wog,
    float* __restrict__ out) {
  __shared__ float tile[16 * 264];
  const int tid = threadIdx.x;
  const int wg = blockIdx.x;
  if (wg == 0 && tid == 0) out[0] = 0.f;
  if (wg < 800) {                     // W1: wg = t*16 + nt
    const int t = wg >> 4, nt = wg & 15;
    const float* src = W1 + ((size_t)t * HH + nt * 16) * SS;
    const float* bsrc = b1 + t * HH + nt * 16;
    for (int i = tid; i < 16 * K1; i += 256) {
      int m = i >> 7, k = i & 127;
      float v = (k < SS) ? src[m * SS + k] : (k == SS ? bsrc[m] : 0.f);
      tile[m * 264 + k] = v;
    }
    __syncthreads();
    {
      int ks = tid >> 6, lane = tid & 63;
      int qq = lane >> 4, cc = lane & 15;
      bf16x8 v;
#pragma unroll
      for (int j = 0; j < 8; ++j) v[j] = f2b(tile[cc * 264 + ks * 32 + qq * 8 + j]);
      *(bf16x8*)&W1g[W1G_OFF(t, nt, ks) + lane * 8] = v;
    }
  } else if (wg < 1600) {             // W2
    const int h = wg - 800;
    const int t = h >> 4, nt = h & 15;
    const float* src = W2 + ((size_t)t * HH + nt * 16) * HH;
    for (int i = tid; i < 16 * HH; i += 256) {
      int m = i >> 8, k = i & 255;
      tile[m * 264 + k] = src[m * HH + k];
    }
    __syncthreads();
    for (int gi = tid; gi < 512; gi += 256) {
      int ks = gi >> 6, lane = gi & 63;
      int qq = lane >> 4, cc = lane & 15;
      bf16x8 v;
#pragma unroll
      for (int j = 0; j < 8; ++j) v[j] = f2b(tile[cc * 264 + ks * 32 + qq * 8 + j]);
      *(bf16x8*)&W2g[W2G_OFF(t, nt, ks) + lane * 8] = v;
    }
  } else {                            // Wo (N padded 100->128)
    const int h = wg - 1600;
    const int t = h >> 3, nt = h & 7;
    for (int i = tid; i < 16 * HH; i += 256) {
      int m = i >> 8, k = i & 255;
      int n = nt * 16 + m;
      tile[m * 264 + k] = (n < SS) ? Wo[((size_t)t * SS + n) * HH + k] : 0.f;
    }
    __syncthreads();
    for (int gi = tid; gi < 512; gi += 256) {
      int ks = gi >> 6, lane = gi & 63;
      int qq = lane >> 4, cc = lane & 15;
      bf16x8 v;
#pragma unroll
      for (int j = 0; j < 8; ++j) v[j] = f2b(tile[cc * 264 + ks * 32 + qq * 8 + j]);
      *(bf16x8*)&Wog[WOG_OFF(t, nt, ks) + lane * 8] = v;
    }
  }
}

// Persistent kernel: 256 blocks x 8 waves; block owns 16 batch rows.
// W2[t] is staged via async global_load_lds (issued after GEMM1, retires
// across LN1's lgkm-only barriers, drained by one vmcnt(0) before GEMM2).
// The staging region is per-wave-private: no barrier is needed for it.
template <int MODE>
__global__ __launch_bounds__(NTHR, 1) void run_kernel(
    const float* __restrict__ s0, const float* __restrict__ prices,
    const float* __restrict__ b1, const float* __restrict__ g1, const float* __restrict__ be1,
    const float* __restrict__ b2, const float* __restrict__ g2, const float* __restrict__ be2,
    const float* __restrict__ bo,
    const float* __restrict__ W1f, const float* __restrict__ W2f, const float* __restrict__ Wof,
    const short* __restrict__ W1g, const short* __restrict__ W2g, const short* __restrict__ Wog,
    float* __restrict__ out) {
  __shared__ short w2s[8][16][512];   // 128KB: per-wave W2 fragment staging
  __shared__ short sbuf[MROWS][K1 + 8];
  __shared__ short xb1[MROWS][HH + 8];
  __shared__ short xb2[MROWS][HH + 8];
  __shared__ float lnred[MROWS][17];
  __shared__ float wsum[8];

  const int tid = threadIdx.x;
  const int w = tid >> 6;
  const int lane = tid & 63;
  const int q = lane >> 4;
  const int c16 = lane & 15;
  const int b0 = blockIdx.x * MROWS;

  const int n0 = w * 32 + c16;   // GEMM1/2 n-tile cols (tiles 2w, 2w+1)
  const int n1 = n0 + 16;
  const int col = w * 16 + c16;  // GEMM3 / epilogue col (tile w)
  const bool cvalid = col < SS;

  for (int j = tid; j < MROWS * (K1 + 8); j += NTHR) ((short*)sbuf)[j] = 0;
  __syncthreads();

  float s_reg[4];
#pragma unroll
  for (int r = 0; r < 4; ++r) {
    int row = q * 4 + r;
    s_reg[r] = cvalid ? s0[(size_t)(b0 + row) * SS + col] : 0.f;
    if (cvalid) sbuf[row][col] = f2b(s_reg[r]);
  }
  __syncthreads();

  bf16x8 w1f[8];
  auto loadW1 = [&](int t) {
#pragma unroll
    for (int ks = 0; ks < 4; ++ks) {
      if (MODE == 0) {
        w1f[2 * ks + 0] = *(const bf16x8*)&W1g[W1G_OFF(t, 2 * w, ks) + lane * 8];
        w1f[2 * ks + 1] = *(const bf16x8*)&W1g[W1G_OFF(t, 2 * w + 1, ks) + lane * 8];
      } else {
        const int k = ks * 32 + q * 8;
        w1f[2 * ks + 0] = ldpad(W1f + ((size_t)t * HH + n0) * SS, k, SS);
        w1f[2 * ks + 1] = ldpad(W1f + ((size_t)t * HH + n1) * SS, k, SS);
      }
    }
  };
  float pr[4];
  auto loadP = [&](int t) {
#pragma unroll
    for (int r = 0; r < 4; ++r) {
      int row = q * 4 + r;
      pr[r] = cvalid ? prices[((size_t)(b0 + row) * TT + t) * SS + col] : 0.f;
    }
  };

  auto ln_epi = [&](f32x4& a0, f32x4& a1, float bv0, float bv1, float gv0, float gv1,
                    float ev0, float ev1, short (*dst)[HH + 8]) {
    float p1[4], p2[4];
#pragma unroll
    for (int r = 0; r < 4; ++r) {
      float v0 = a0[r] + bv0;
      float v1 = a1[r] + bv1;
      a0[r] = v0;
      a1[r] = v1;
      p1[r] = v0 + v1;
      p2[r] = v0 * v0 + v1 * v1;
    }
#pragma unroll
    for (int m = 1; m <= 8; m <<= 1)
#pragma unroll
      for (int r = 0; r < 4; ++r) {
        p1[r] += __shfl_xor(p1[r], m);
        p2[r] += __shfl_xor(p2[r], m);
      }
    if (c16 == 0) {
#pragma unroll
      for (int r = 0; r < 4; ++r) {
        lnred[q * 4 + r][2 * w] = p1[r];
        lnred[q * 4 + r][2 * w + 1] = p2[r];
      }
    }
    bar_lds();
    float meanv = 0.f, rstdv = 0.f;
    if (lane < 16) {
      float S1 = 0.f, S2 = 0.f;
#pragma unroll
      for (int i = 0; i < 8; ++i) {
        S1 += lnred[lane][2 * i];
        S2 += lnred[lane][2 * i + 1];
      }
      meanv = S1 * (1.f / HH);
      float var = fmaxf(S2 * (1.f / HH) - meanv * meanv, 0.f);
      rstdv = rsqrtf(var + 1e-5f);
    }
#pragma unroll
    for (int r = 0; r < 4; ++r) {
      int row = q * 4 + r;
      float mean = __shfl(meanv, row);
      float rstd = __shfl(rstdv, row);
      float v0 = (a0[r] - mean) * rstd * gv0 + ev0;
      float v1 = (a1[r] - mean) * rstd * gv1 + ev1;
      dst[row][n0] = f2b(fmaxf(v0, 0.f));
      dst[row][n1] = f2b(fmaxf(v1, 0.f));
    }
    bar_lds();
  };

  loadW1(0);
  loadP(0);
  float costreg = 0.f;

#pragma unroll 1
  for (int t = 0; t < NSTEP; ++t) {
    const float b1v0 = b1[t * HH + n0], b1v1 = b1[t * HH + n1];
    const float g1v0 = g1[t * HH + n0], g1v1 = g1[t * HH + n1];
    const float e1v0 = be1[t * HH + n0], e1v1 = be1[t * HH + n1];
    const float b2v0 = b2[t * HH + n0], b2v1 = b2[t * HH + n1];
    const float g2v0 = g2[t * HH + n0], g2v1 = g2[t * HH + n1];
    const float e2v0 = be2[t * HH + n0], e2v1 = be2[t * HH + n1];
    const float bov = cvalid ? bo[t * SS + col] : 0.f;

    // ===== GEMM1: h1[16x256] = s @ W1[t].T =====
    f32x4 acc0 = (f32x4){0.f, 0.f, 0.f, 0.f};
    f32x4 acc1 = (f32x4){0.f, 0.f, 0.f, 0.f};
#pragma unroll
    for (int ks = 0; ks < 4; ++ks) {
      bf16x8 a = *(const bf16x8*)&sbuf[c16][ks * 32 + q * 8];
      acc0 = MFMA(a, w1f[2 * ks + 0], acc0);
      acc1 = MFMA(a, w1f[2 * ks + 1], acc1);
    }

    // Async-stage W2[t] into this wave's private LDS region. DMA consumes no
    // VGPRs, cannot be sunk (side effect), and flies across LN1's barriers.
    if (MODE == 0) {
#pragma unroll
      for (int ks = 0; ks < 8; ++ks) {
        __builtin_amdgcn_global_load_lds(
            (const uint32_t*)&W2g[W2G_OFF(t, 2 * w, ks) + lane * 8],
            (uint32_t*)&w2s[w][2 * ks][0], 16, 0, 0);
        __builtin_amdgcn_global_load_lds(
            (const uint32_t*)&W2g[W2G_OFF(t, 2 * w + 1, ks) + lane * 8],
            (uint32_t*)&w2s[w][2 * ks + 1][0], 16, 0, 0);
      }
    }

    ln_epi(acc0, acc1, b1v0, b1v1, g1v0, g1v1, e1v0, e1v1, xb1);

    // ===== GEMM2: h2[16x256] = x1 @ W2[t].T (B frags from staged LDS) =====
    if (MODE == 0) wait_vm0();
    f32x4 acc0b = (f32x4){0.f, 0.f, 0.f, 0.f};
    f32x4 acc1b = (f32x4){0.f, 0.f, 0.f, 0.f};
    acc0 = (f32x4){0.f, 0.f, 0.f, 0.f};
    acc1 = (f32x4){0.f, 0.f, 0.f, 0.f};
#pragma unroll
    for (int ks = 0; ks < 4; ++ks) {
      bf16x8 a = *(const bf16x8*)&xb1[c16][ks * 32 + q * 8];
      bf16x8 bA, bB;
      if (MODE == 0) {
        bA = *(const bf16x8*)&w2s[w][2 * ks + 0][lane * 8];
        bB = *(const bf16x8*)&w2s[w][2 * ks + 1][lane * 8];
      } else {
        const int k = ks * 32 + q * 8;
        bA = cvt8(W2f + ((size_t)t * HH + n0) * HH + k);
        bB = cvt8(W2f + ((size_t)t * HH + n1) * HH + k);
      }
      acc0 = MFMA(a, bA, acc0);
      acc1 = MFMA(a, bB, acc1);
    }
#pragma unroll
    for (int ks = 4; ks < 8; ++ks) {
      bf16x8 a = *(const bf16x8*)&xb1[c16][ks * 32 + q * 8];
      bf16x8 bA, bB;
      if (MODE == 0) {
        bA = *(const bf16x8*)&w2s[w][2 * ks + 0][lane * 8];
        bB = *(const bf16x8*)&w2s[w][2 * ks + 1][lane * 8];
      } else {
        const int k = ks * 32 + q * 8;
        bA = cvt8(W2f + ((size_t)t * HH + n0) * HH + k);
        bB = cvt8(W2f + ((size_t)t * HH + n1) * HH + k);
      }
      acc0b = MFMA(a, bA, acc0b);
      acc1b = MFMA(a, bB, acc1b);
    }
    acc0 = acc0 + acc0b;
    acc1 = acc1 + acc1b;

    // Wo[t] register loads (issued here, hopefully overlap LN2)
    bf16x8 wof[8];
#pragma unroll
    for (int ks = 0; ks < 8; ++ks) {
      if (MODE == 0) {
        wof[ks] = *(const bf16x8*)&Wog[WOG_OFF(t, w, ks) + lane * 8];
      } else {
        const int k = ks * 32 + q * 8;
        if (cvalid) {
          wof[ks] = cvt8(Wof + ((size_t)t * SS + col) * HH + k);
        } else {
          bf16x8 z = {0, 0, 0, 0, 0, 0, 0, 0};
          wof[ks] = z;
        }
      }
    }

    ln_epi(acc0, acc1, b2v0, b2v1, g2v0, g2v1, e2v0, e2v1, xb2);

    // ===== GEMM3: o[16x(100p128)] = x2 @ Wo[t].T (split acc chains) =====
    f32x4 a3 = (f32x4){0.f, 0.f, 0.f, 0.f};
    f32x4 a3b = (f32x4){0.f, 0.f, 0.f, 0.f};
#pragma unroll
    for (int ks = 0; ks < 4; ++ks) {
      bf16x8 a = *(const bf16x8*)&xb2[c16][ks * 32 + q * 8];
      a3 = MFMA(a, wof[ks], a3);
    }
#pragma unroll
    for (int ks = 4; ks < 8; ++ks) {
      bf16x8 a = *(const bf16x8*)&xb2[c16][ks * 32 + q * 8];
      a3b = MFMA(a, wof[ks], a3b);
    }
    a3 = a3 + a3b;

    // next-step W1 + prices
    float pcur[4];
#pragma unroll
    for (int r = 0; r < 4; ++r) pcur[r] = pr[r];
    const int tn = (t + 1 < NSTEP) ? t + 1 : 0;
    loadW1(tn);
    loadP(t + 1);

    // ===== epilogue =====
#pragma unroll
    for (int r = 0; r < 4; ++r) {
      float o = a3[r] + bov;
      float a = fminf(o, s_reg[r]);
      float pa = pcur[r] * a;
      costreg += pa + 0.01f * pa * pa;
      s_reg[r] -= a;
      if (cvalid) sbuf[q * 4 + r][col] = f2b(s_reg[r]);
    }
    bar_lds();
  }

  // ===== terminal =====
#pragma unroll
  for (int r = 0; r < 4; ++r) {
    float pa = pr[r] * s_reg[r];
    costreg += pa + 0.01f * pa * pa;
  }

#pragma unroll
  for (int m = 1; m < 64; m <<= 1) costreg += __shfl_xor(costreg, m);
  if (lane == 0) wsum[w] = costreg;
  __syncthreads();
  if (tid == 0) {
    float tot = 0.f;
#pragma unroll
    for (int i = 0; i < 8; ++i) tot += wsum[i];
    atomicAdd(out, tot * (1.f / NBATCH));
  }
}

extern "C" void kernel_launch(void* const* d_in, const int* in_sizes, int n_in,
                              void* d_out, int out_size, void* d_ws, size_t ws_size,
                              hipStream_t stream) {
  const float* s0 = (const float*)d_in[0];
  const float* prices = (const float*)d_in[1];
  const float* W1 = (const float*)d_in[2];
  const float* b1 = (const float*)d_in[3];
  const float* g1 = (const float*)d_in[4];
  const float* be1 = (const float*)d_in[5];
  const float* W2 = (const float*)d_in[6];
  const float* b2 = (const float*)d_in[7];
  const float* g2 = (const float*)d_in[8];
  const float* be2 = (const float*)d_in[9];
  const float* Wo = (const float*)d_in[10];
  const float* bo = (const float*)d_in[11];
  float* out = (float*)d_out;

  const size_t need = (N_W1G + N_W2G + N_WOG) * sizeof(short);

  if (ws_size >= need) {
    short* W1g = (short*)d_ws;
    short* W2g = W1g + N_W1G;
    short* Wog = W2g + N_W2G;
    prep<<<dim3(2000), dim3(256), 0, stream>>>(W1, b1, W2, Wo, W1g, W2g, Wog, out);
    run_kernel<0><<<dim3(NBLK), dim3(NTHR), 0, stream>>>(
        s0, prices, b1, g1, be1, b2, g2, be2, bo,
        W1, W2, Wo, W1g, W2g, Wog, out);
  } else {
    zero_out<<<dim3(1), dim3(64), 0, stream>>>(out);
    run_kernel<1><<<dim3(256), dim3(NTHR), 0, stream>>>(
        s0, prices, b1, g1, be1, b2, g2, be2, bo,
        W1, W2, Wo, (const short*)nullptr, (const short*)nullptr, (const short*)nullptr, out);
  }
}